// Round 6
// baseline (74.445 us; speedup 1.0000x reference)
//
#include <hip/hip_runtime.h>
#include <hip/hip_bf16.h>

#define S_ 8192
#define H_ 8
#define D_ 64
#define M_ 64
#define BH_ 32
#define CPK_ 80          // buf1/partial row stride (c 0..79, den at c=64)
#define NCH_ 16          // phase-K chunks
#define ITERS_ 4         // 32-row chunks per wave: 512 rows / (4 waves * 32)
#define NCHQ 16
#define TILE 64
#define QTILES (S_ / NCHQ / TILE)   // 8

typedef short bf16x8 __attribute__((ext_vector_type(8)));
typedef float f32x4 __attribute__((ext_vector_type(4)));

constexpr float XS_ = 0.35355339059327373f * 1.4426950408889634f; // D^-1/4 * log2(e)
constexpr float HS_ = 0.34657359027997264f;                        // ln2/2
constexpr float EPS_ = 1e-6f;

__device__ __forceinline__ unsigned short f2bf(float f) {
    unsigned int u = __float_as_uint(f);
    u += 0x7FFFu + ((u >> 16) & 1u);          // RNE
    return (unsigned short)(u >> 16);
}
// paired RNE conversion -> v_cvt_pk_bf16_f32 (lo in low 16 bits)
__device__ __forceinline__ unsigned int pkbf(float lo, float hi) {
    __hip_bfloat162 t = __float22bfloat162_rn(float2{lo, hi});
    return *reinterpret_cast<unsigned int*>(&t);
}
__device__ __forceinline__ float fexp2(float x) { return __builtin_amdgcn_exp2f(x); }

#define MFMA(a, b, c) __builtin_amdgcn_mfma_f32_16x16x32_bf16((a), (b), (c), 0, 0, 0)
#define SWZ(byteoff, row) ((byteoff) ^ (((row) & 7) << 4))

// ---------------------------------------------------------------------------
// Phase K — BARRIER-FREE main loop. Each wave independently processes 32-row
// chunks: P = mfma(Kscaled, projT) leaves E in registers in exactly the
// A-operand layout needed for the second MFMA (k-slot permutation
// sigma(g,j) = 16*(j>>2) + 4g + (j&3), legal because V is stored to
// wave-private LDS in the SAME sigma slot order). acc[m][c] accumulated
// per-wave over its rows; one cross-wave LDS reduce at kernel end.
// No __syncthreads in the loop => no vmcnt(0) drain => prefetch survives.
// ---------------------------------------------------------------------------
__global__ void __launch_bounds__(256, 2)
fa_k(const float* __restrict__ ks, const float* __restrict__ vs,
     const float* __restrict__ proj, float* __restrict__ partial)
{
    const int chunk = blockIdx.x;
    const int bh    = blockIdx.y;
    const int b = bh >> 3, h = bh & 7;
    const int tid = threadIdx.x, wid = tid >> 6, lane = tid & 63;
    const int l15 = lane & 15, g = lane >> 4;

    __shared__ __align__(16) char vW[4][2][64 * 64]; // [wave][buf][c] 32 bf16 slots
    __shared__ float red[M_ * CPK_];

    const size_t rs = (size_t)H_ * D_;
    const float* kb = ks + ((size_t)b * S_ * H_ + h) * D_;
    const float* vb = vs + ((size_t)b * S_ * H_ + h) * D_;
    const int rbase = chunk * (ITERS_ * 128) + wid * 32;

    // proj B-fragments: B[k=d][n=m]: lane: m = mt*16+l15, d = g*8+j (+32*kk)
    bf16x8 pf[4][2];
#pragma unroll
    for (int mt = 0; mt < 4; ++mt)
#pragma unroll
        for (int kk = 0; kk < 2; ++kk) {
            const float* p = proj + (mt * 16 + l15) * D_ + kk * 32 + g * 8;
            float4 a = *(const float4*)p, c = *(const float4*)(p + 4);
            union { bf16x8 v; unsigned int u[4]; } F;
            F.u[0] = pkbf(a.x, a.y); F.u[1] = pkbf(a.z, a.w);
            F.u[2] = pkbf(c.x, c.y); F.u[3] = pkbf(c.z, c.w);
            pf[mt][kk] = F.v;
        }

    // ones-column B-frag: B[k][c]=1 iff c==64 (lane l15==0); sigma-invariant
    bf16x8 onef = {0, 0, 0, 0, 0, 0, 0, 0};
    if (l15 == 0) {
#pragma unroll
        for (int j = 0; j < 8; ++j) onef[j] = (short)0x3F80;
    }

    f32x4 acc[4][5];
#pragma unroll
    for (int mt = 0; mt < 4; ++mt)
#pragma unroll
        for (int ci = 0; ci < 5; ++ci) acc[mt][ci] = (f32x4){0.f, 0.f, 0.f, 0.f};

    // load 2 subtiles (s=0,1): row rbase + t*128 + s*16 + l15, 16 cols per lane
    auto loadX = [&](const float* xb, int t, float4* xp) {
        const float* r0 = xb + (size_t)(rbase + t * 128 + l15) * rs;
        xp[0] = *(const float4*)(r0 + g * 8);
        xp[1] = *(const float4*)(r0 + g * 8 + 4);
        xp[2] = *(const float4*)(r0 + 32 + g * 8);
        xp[3] = *(const float4*)(r0 + 32 + g * 8 + 4);
        const float* r1 = r0 + 16 * rs;
        xp[4] = *(const float4*)(r1 + g * 8);
        xp[5] = *(const float4*)(r1 + g * 8 + 4);
        xp[6] = *(const float4*)(r1 + 32 + g * 8);
        xp[7] = *(const float4*)(r1 + 32 + g * 8 + 4);
    };

    // store V rows into wave-private LDS in sigma slot order:
    // slot(row = 16s + l15) = ((l15>>2)&3)*8 + 4s + (l15&3)
    auto storeV = [&](const float4* vp, int buf) {
        char* base = (char*)vW + wid * 8192 + buf * 4096;
        int id0 = ((l15 >> 2) & 3) * 8 + (l15 & 3);
#pragma unroll
        for (int s = 0; s < 2; ++s) {
            int id = id0 + 4 * s;
            float vv[16];
#pragma unroll
            for (int i = 0; i < 4; ++i) {
                float4 q = vp[4 * s + i];
                vv[4 * i + 0] = q.x; vv[4 * i + 1] = q.y;
                vv[4 * i + 2] = q.z; vv[4 * i + 3] = q.w;
            }
#pragma unroll
            for (int p2 = 0; p2 < 4; ++p2) {
                int cA = g * 8 + 2 * p2;
                unsigned int pA = pkbf(vv[2 * p2], vv[2 * p2 + 1]);
                *(unsigned short*)(base + cA * 64 + ((2 * id) ^ ((cA & 3) << 4))) =
                    (unsigned short)pA;
                int cB = cA + 1;
                *(unsigned short*)(base + cB * 64 + ((2 * id) ^ ((cB & 3) << 4))) =
                    (unsigned short)(pA >> 16);
                int cC = 32 + cA;
                unsigned int pB = pkbf(vv[8 + 2 * p2], vv[9 + 2 * p2]);
                *(unsigned short*)(base + cC * 64 + ((2 * id) ^ ((cC & 3) << 4))) =
                    (unsigned short)pB;
                int cD = cC + 1;
                *(unsigned short*)(base + cD * 64 + ((2 * id) ^ ((cD & 3) << 4))) =
                    (unsigned short)(pB >> 16);
            }
        }
    };

    auto body = [&](int t, const float4* kc, float4* kn, float4* vn) {
        if (t + 1 < ITERS_) { loadX(kb, t + 1, kn); loadX(vb, t + 1, vn); }

        // scale + per-row h for both subtiles
        float kx0[16], kx1[16];
#pragma unroll
        for (int i = 0; i < 4; ++i) {
            kx0[4*i+0] = kc[i].x * XS_; kx0[4*i+1] = kc[i].y * XS_;
            kx0[4*i+2] = kc[i].z * XS_; kx0[4*i+3] = kc[i].w * XS_;
            kx1[4*i+0] = kc[4+i].x * XS_; kx1[4*i+1] = kc[4+i].y * XS_;
            kx1[4*i+2] = kc[4+i].z * XS_; kx1[4*i+3] = kc[4+i].w * XS_;
        }
        float sq0 = 0.f, sq1 = 0.f;
#pragma unroll
        for (int j = 0; j < 16; ++j) { sq0 += kx0[j]*kx0[j]; sq1 += kx1[j]*kx1[j]; }
        sq0 += __shfl_xor(sq0, 16); sq0 += __shfl_xor(sq0, 32);
        sq1 += __shfl_xor(sq1, 16); sq1 += __shfl_xor(sq1, 32);
        float h0 = sq0 * HS_ + 3.0f, h1 = sq1 * HS_ + 3.0f;

        union { bf16x8 v; unsigned int u[4]; } A00, A01, A10, A11;
#pragma unroll
        for (int i = 0; i < 4; ++i) {
            A00.u[i] = pkbf(kx0[2*i], kx0[2*i+1]);
            A01.u[i] = pkbf(kx0[8+2*i], kx0[9+2*i]);
            A10.u[i] = pkbf(kx1[2*i], kx1[2*i+1]);
            A11.u[i] = pkbf(kx1[8+2*i], kx1[9+2*i]);
        }

        f32x4 pa0[4], pa1[4];
#pragma unroll
        for (int mt = 0; mt < 4; ++mt) {
            pa0[mt] = (f32x4){0.f, 0.f, 0.f, 0.f};
            pa0[mt] = MFMA(A00.v, pf[mt][0], pa0[mt]);
            pa0[mt] = MFMA(A01.v, pf[mt][1], pa0[mt]);
            pa1[mt] = (f32x4){0.f, 0.f, 0.f, 0.f};
            pa1[mt] = MFMA(A10.v, pf[mt][0], pa1[mt]);
            pa1[mt] = MFMA(A11.v, pf[mt][1], pa1[mt]);
        }

        float hr0[4], hr1[4];
#pragma unroll
        for (int r = 0; r < 4; ++r) {
            hr0[r] = __shfl(h0, 4 * g + r);
            hr1[r] = __shfl(h1, 4 * g + r);
        }

        // E in registers, already in A-frag sigma layout: slots 0..3 from s=0,
        // slots 4..7 from s=1 (rows 4g+r), m = mt*16 + l15
        bf16x8 eA[4];
#pragma unroll
        for (int mt = 0; mt < 4; ++mt) {
            union { bf16x8 v; unsigned int u[4]; } E;
            E.u[0] = pkbf(fexp2(pa0[mt][0]-hr0[0]), fexp2(pa0[mt][1]-hr0[1]));
            E.u[1] = pkbf(fexp2(pa0[mt][2]-hr0[2]), fexp2(pa0[mt][3]-hr0[3]));
            E.u[2] = pkbf(fexp2(pa1[mt][0]-hr1[0]), fexp2(pa1[mt][1]-hr1[1]));
            E.u[3] = pkbf(fexp2(pa1[mt][2]-hr1[2]), fexp2(pa1[mt][3]-hr1[3]));
            eA[mt] = E.v;
        }

        // V^T B-frags from wave-private LDS (same-wave RAW: lgkmcnt only)
        const char* rb2 = (const char*)vW + wid * 8192 + (t & 1) * 4096;
        bf16x8 vB[4];
#pragma unroll
        for (int ct = 0; ct < 4; ++ct) {
            int c = ct * 16 + l15;
            vB[ct] = *(const bf16x8*)(rb2 + c * 64 + ((16 * g) ^ ((c & 3) << 4)));
        }
#pragma unroll
        for (int mt = 0; mt < 4; ++mt) {
#pragma unroll
            for (int ct = 0; ct < 4; ++ct)
                acc[mt][ct] = MFMA(eA[mt], vB[ct], acc[mt][ct]);
            acc[mt][4] = MFMA(eA[mt], onef, acc[mt][4]);
        }

        if (t + 1 < ITERS_) storeV(vn, (t + 1) & 1);
    };

    float4 k0[8], k1[8], v0[8], v1[8];
    loadX(kb, 0, k0);
    loadX(vb, 0, v0);
    storeV(v0, 0);
    body(0, k0, k1, v1);
    body(1, k1, k0, v0);
    body(2, k0, k1, v1);
    body(3, k1, k0, v0);

    // cross-wave reduce (only barriers in the kernel), then write partial
    for (int i = tid; i < M_ * CPK_; i += 256) red[i] = 0.f;
    __syncthreads();
    for (int w = 0; w < 4; ++w) {
        if (wid == w) {
#pragma unroll
            for (int mt = 0; mt < 4; ++mt)
#pragma unroll
                for (int ct = 0; ct < 5; ++ct)
#pragma unroll
                    for (int r = 0; r < 4; ++r)
                        red[(mt*16 + 4*g + r) * CPK_ + ct*16 + l15] += acc[mt][ct][r];
        }
        __syncthreads();
    }
    float* dst = partial + ((size_t)bh * NCH_ + chunk) * (M_ * CPK_);
    for (int i = tid; i < M_ * CPK_; i += 256) dst[i] = red[i];
}

// ---------------------------------------------------------------------------
// Reduce partials over chunks -> buf1[bh][m][CPK_]
// ---------------------------------------------------------------------------
__global__ void __launch_bounds__(256)
fa_r(const float* __restrict__ partial, float* __restrict__ buf1, int nch)
{
    int e = blockIdx.x * 256 + threadIdx.x;
    if (e >= BH_ * M_ * CPK_) return;
    int bh = e / (M_ * CPK_);
    int r  = e - bh * (M_ * CPK_);
    const float* src = partial + (size_t)bh * nch * (M_ * CPK_) + r;
    float s0 = 0.f, s1 = 0.f, s2 = 0.f, s3 = 0.f;
    int ch = 0;
    for (; ch + 4 <= nch; ch += 4) {
        s0 += src[(size_t)(ch + 0) * (M_ * CPK_)];
        s1 += src[(size_t)(ch + 1) * (M_ * CPK_)];
        s2 += src[(size_t)(ch + 2) * (M_ * CPK_)];
        s3 += src[(size_t)(ch + 3) * (M_ * CPK_)];
    }
    for (; ch < nch; ++ch) s0 += src[(size_t)ch * (M_ * CPK_)];
    buf1[e] = (s0 + s1) + (s2 + s3);
}

// ---------------------------------------------------------------------------
// Phase Q: P = mfma(Qscaled, projT); e = exp2(P - h);
// Out^T-tiles: D[c][qrow] = mfma(buf1T, E_T); den = row c=64; out = num/den.
// ---------------------------------------------------------------------------
__global__ void __launch_bounds__(256)
fa_q(const float* __restrict__ qs, const float* __restrict__ proj,
     const float* __restrict__ buf1, float* __restrict__ out)
{
    const int chunk = blockIdx.x;
    const int bh    = blockIdx.y;
    const int b = bh >> 3, h = bh & 7;
    const int tid = threadIdx.x, wid = tid >> 6, lane = tid & 63;
    const int l15 = lane & 15, g = lane >> 4;

    __shared__ __align__(16) char eLb[2][TILE * M_ * 2];   // [qrow][m] bf16, swz by qrow
    __shared__ __align__(16) char b1tb[CPK_ * M_ * 2];     // [c][m] bf16, swz by c

    const int rows = S_ / NCHQ;
    const int s0 = chunk * rows;
    const size_t rs = (size_t)H_ * D_;
    const float* qb = qs + ((size_t)b * S_ * H_ + h) * D_;

    // stage buf1^T into LDS (c rows 65..79 are zeros in buf1 already)
    const float* b1 = buf1 + (size_t)bh * (M_ * CPK_);
    for (int i = tid; i < M_ * CPK_; i += 256) {
        int m = i / CPK_, c = i - m * CPK_;
        *(unsigned short*)(b1tb + SWZ(c * 128 + 2 * m, c)) = f2bf(b1[i]);
    }

    bf16x8 pf[4][2];
#pragma unroll
    for (int mt = 0; mt < 4; ++mt)
#pragma unroll
        for (int kk = 0; kk < 2; ++kk) {
            const float* p = proj + (mt * 16 + l15) * D_ + kk * 32 + g * 8;
            float4 a = *(const float4*)p, c = *(const float4*)(p + 4);
            union { bf16x8 v; unsigned int u[4]; } F;
            F.u[0] = pkbf(a.x, a.y); F.u[1] = pkbf(a.z, a.w);
            F.u[2] = pkbf(c.x, c.y); F.u[3] = pkbf(c.z, c.w);
            pf[mt][kk] = F.v;
        }
    __syncthreads();

    // buf1^T A-fragments, read once: A[c][m]: c = ci*16+l15, m = g*8+j (+32*kk)
    bf16x8 af3[5][2];
#pragma unroll
    for (int ci = 0; ci < 5; ++ci)
#pragma unroll
        for (int kk = 0; kk < 2; ++kk) {
            int c = ci * 16 + l15;
            af3[ci][kk] = *(const bf16x8*)(b1tb + SWZ(c * 128 + 16 * g + 64 * kk, c));
        }

    auto loadQ = [&](int t, float4* qp) {
        int sb = s0 + t * TILE;
        const float* qrow = qb + (size_t)(sb + wid * 16 + l15) * rs;
        qp[0] = *(const float4*)(qrow + g * 8);
        qp[1] = *(const float4*)(qrow + g * 8 + 4);
        qp[2] = *(const float4*)(qrow + 32 + g * 8);
        qp[3] = *(const float4*)(qrow + 32 + g * 8 + 4);
    };

    auto body = [&](int t, int p, const float4* qc, float4* qn) {
        if (t + 1 < QTILES) loadQ(t + 1, qn);

        float kx[16];
#pragma unroll
        for (int i = 0; i < 4; ++i) {
            kx[4 * i + 0] = qc[i].x * XS_; kx[4 * i + 1] = qc[i].y * XS_;
            kx[4 * i + 2] = qc[i].z * XS_; kx[4 * i + 3] = qc[i].w * XS_;
        }
        float sq = 0.f;
#pragma unroll
        for (int j = 0; j < 16; ++j) sq += kx[j] * kx[j];
        sq += __shfl_xor(sq, 16);
        sq += __shfl_xor(sq, 32);
        float hrow = sq * HS_ + 3.0f;

        union { bf16x8 v; unsigned int u[4]; } A0, A1;
#pragma unroll
        for (int i = 0; i < 4; ++i) {
            A0.u[i] = pkbf(kx[2 * i], kx[2 * i + 1]);
            A1.u[i] = pkbf(kx[8 + 2 * i], kx[9 + 2 * i]);
        }

        f32x4 pa[4];
#pragma unroll
        for (int mt = 0; mt < 4; ++mt) {
            pa[mt] = (f32x4){0.f, 0.f, 0.f, 0.f};
            pa[mt] = MFMA(A0.v, pf[mt][0], pa[mt]);
            pa[mt] = MFMA(A1.v, pf[mt][1], pa[mt]);
        }

        float hr[4];
#pragma unroll
        for (int r = 0; r < 4; ++r) hr[r] = __shfl(hrow, 4 * g + r);

        char* elp = eLb[p];
#pragma unroll
        for (int mt = 0; mt < 4; ++mt) {
            int m = mt * 16 + l15;
            float e0 = fexp2(pa[mt][0] - hr[0]);
            float e1 = fexp2(pa[mt][1] - hr[1]);
            float e2 = fexp2(pa[mt][2] - hr[2]);
            float e3 = fexp2(pa[mt][3] - hr[3]);
            unsigned int p01 = pkbf(e0, e1), p23 = pkbf(e2, e3);
            int q0 = wid * 16 + 4 * g;
            *(unsigned short*)(elp + SWZ((q0 + 0) * 128 + 2 * m, q0 + 0)) =
                (unsigned short)p01;
            *(unsigned short*)(elp + SWZ((q0 + 1) * 128 + 2 * m, q0 + 1)) =
                (unsigned short)(p01 >> 16);
            *(unsigned short*)(elp + SWZ((q0 + 2) * 128 + 2 * m, q0 + 2)) =
                (unsigned short)p23;
            *(unsigned short*)(elp + SWZ((q0 + 3) * 128 + 2 * m, q0 + 3)) =
                (unsigned short)(p23 >> 16);
        }
        __syncthreads();

        bf16x8 b3[2];
        {
            int qrow = wid * 16 + l15;
            b3[0] = *(const bf16x8*)(elp + SWZ(qrow * 128 + 16 * g, qrow));
            b3[1] = *(const bf16x8*)(elp + SWZ(qrow * 128 + 16 * g + 64, qrow));
        }
        f32x4 dt[5];
#pragma unroll
        for (int ci = 0; ci < 5; ++ci) {
            dt[ci] = (f32x4){0.f, 0.f, 0.f, 0.f};
            dt[ci] = MFMA(af3[ci][0], b3[0], dt[ci]);
            dt[ci] = MFMA(af3[ci][1], b3[1], dt[ci]);
        }

        float den = __shfl(dt[4][0], l15);      // lanes g==0 hold den[qrow=l15]
        float rd = 1.0f / fmaxf(den, EPS_);

        int sg = s0 + t * TILE + wid * 16 + l15;
        size_t base = (((size_t)b * S_ + sg) * H_ + h) * D_;
#pragma unroll
        for (int ci = 0; ci < 4; ++ci) {
            f32x4 o;
#pragma unroll
            for (int r = 0; r < 4; ++r) o[r] = dt[ci][r] * rd;
            *(f32x4*)(out + base + ci * 16 + 4 * g) = o;
        }
    };

    float4 qa[4], qb2[4];
    loadQ(0, qa);
    for (int t = 0; t < QTILES; t += 2) {
        body(t, 0, qa, qb2);
        body(t + 1, 1, qb2, qa);
    }
}

extern "C" void kernel_launch(void* const* d_in, const int* in_sizes, int n_in,
                              void* d_out, int out_size, void* d_ws, size_t ws_size,
                              hipStream_t stream)
{
    const float* qs   = (const float*)d_in[0];
    const float* ks   = (const float*)d_in[1];
    const float* vs   = (const float*)d_in[2];
    const float* proj = (const float*)d_in[3];
    float* out = (float*)d_out;

    float* partial = (float*)d_ws;                // BH*NCH_*M*CPK
    float* buf1 = partial + (size_t)BH_ * NCH_ * (M_ * CPK_);

    fa_k<<<dim3(NCH_, BH_), 256, 0, stream>>>(ks, vs, proj, partial);
    int nred = (BH_ * M_ * CPK_ + 255) / 256;
    fa_r<<<dim3(nred), 256, 0, stream>>>(partial, buf1, NCH_);
    fa_q<<<dim3(NCHQ, BH_), 256, 0, stream>>>(qs, proj, buf1, out);
}